// Round 11
// baseline (192.806 us; speedup 1.0000x reference)
//
#include <hip/hip_runtime.h>

// Correlation / cost-volume, fp32.
// corr[b, dy*9+dx, y, x] = (1/128) * sum_c in1[b,c,y,x] * in2[b,c,y+dy-4,x+dx-4]
//
// R18 = R17 minus the pacing s_barrier (single-variable A/B vs R17's
// measured 84 us rocprof / VALUBusy 35.7% / VGPR 68 / FETCH 65.5 MB).
// R17 post-mortem: wall 1575 cyc/chunk vs 430 cyc/chunk per-SIMD issue
// => 64% all-wave stall. Not HBM (16%), not L2-BW (~3 TB/s), not issue.
// Model: L1 line-throughput + barrier convoy. Each wave touches ~80 L1
// lines/chunk (in2 float4s are 16 lanes @ 32B stride: 8 half-consumed
// lines x 4 row-groups x 2 instr = 64, +16 in1); 9 waves x 80 = 720 cyc
// of serial L1 line work per chunk. The barrier synchronized all 36 VMEM
// instrs into a burst each chunk: L1 serializes while compute (428 cyc)
// waits on the stragglers => wall ~ L1-serial + latency ~ 1575. Removing
// the barrier lets waves drift so L1 work overlaps other waves' compute:
// wall -> max(720, 430) + eps. R14's "alignment helps L1 hits" had the
// sign wrong: inputs are L3-resident (FETCH 65 MB < 128 MB inputs), hits
// were never at risk; alignment only created the convoy.
// Everything else identical: NT=576 zero-dead-lane (4ly x 9dy x 16xg),
// TY=4, grid 256 = 1 block/CU, depth-2 register pipeline, DPP x-halos,
// launch_bounds(576,1) => unified cap 170, measured use 68+72acc=140.

#define MAXD 4
#define ND 9
#define NDISP 81
#define BATCH 8
#define CH 128
#define HH 128
#define WW 128
#define HW (HH * WW)
#define NCHUNK CH                 // 1 channel per pipeline stage
#define TY 4
#define NT 576                    // 9 waves; every lane computes

__device__ __forceinline__ float dpp_shr1(float x) {   // lane i <- lane i-1 (row16)
    return __int_as_float(__builtin_amdgcn_update_dpp(
        0, __float_as_int(x), 0x111, 0xF, 0xF, true));
}
__device__ __forceinline__ float dpp_shl1(float x) {   // lane i <- lane i+1 (row16)
    return __int_as_float(__builtin_amdgcn_update_dpp(
        0, __float_as_int(x), 0x101, 0xF, 0xF, true));
}

__global__ __launch_bounds__(NT, 1) void corr_kernel(
    const float* __restrict__ in1,
    const float* __restrict__ in2,
    float* __restrict__ out)
{
    const int tid = threadIdx.x;
    const int b   = blockIdx.x;
    const int y0  = blockIdx.y * TY;
    const int xg  = tid & 15;               // 16 lanes span the 128-px row
    const int dy  = (tid >> 4) % ND;        // 9 dy groups
    const int ly  = tid / 144;              // 0..3: row within tile
    const int rl  = ly + dy;                // in2 row offset consumed (0..11)
    const bool rok = (unsigned)(y0 + rl - MAXD) < (unsigned)HH;
    int r2 = y0 + rl - MAXD;                // clamped row; garbage zeroed at end
    r2 = r2 < 0 ? 0 : (r2 > HH - 1 ? HH - 1 : r2);

    const float* p2 = in2 + (size_t)b * CH * HW + (size_t)r2 * WW + xg * 8;
    const float* p1 = in1 + (size_t)b * CH * HW + (size_t)(y0 + ly) * WW + xg * 8;

    float acc[ND][8];
    #pragma unroll
    for (int d = 0; d < ND; ++d)
        #pragma unroll
        for (int i = 0; i < 8; ++i) acc[d][i] = 0.0f;

    // 2 named pipeline stages (static indexing only -> registers, rule #20)
    float w0[8], a0[8], w1[8], a1[8];

    // load current chunk's 32B of in2 (w) and 32B of in1 (a); advance ptrs
    auto LD = [&](float* w, float* a) {
        float4 t0 = *(const float4*)(p2);
        float4 t1 = *(const float4*)(p2 + 4);
        float4 u0 = *(const float4*)(p1);
        float4 u1 = *(const float4*)(p1 + 4);
        w[0] = t0.x; w[1] = t0.y; w[2] = t0.z; w[3] = t0.w;
        w[4] = t1.x; w[5] = t1.y; w[6] = t1.z; w[7] = t1.w;
        a[0] = u0.x; a[1] = u0.y; a[2] = u0.z; a[3] = u0.w;
        a[4] = u1.x; a[5] = u1.y; a[6] = u1.z; a[7] = u1.w;
        p2 += HW; p1 += HW;
    };

    auto CMP = [&](const float* w, const float* a) {
        float W[16];
        W[0]  = dpp_shr1(w[4]);   // x-4..x-1 from lane-1; 0 at image edge
        W[1]  = dpp_shr1(w[5]);
        W[2]  = dpp_shr1(w[6]);
        W[3]  = dpp_shr1(w[7]);
        #pragma unroll
        for (int i = 0; i < 8; ++i) W[4 + i] = w[i];
        W[12] = dpp_shl1(w[0]);   // x+8..x+11 from lane+1; 0 at image edge
        W[13] = dpp_shl1(w[1]);
        W[14] = dpp_shl1(w[2]);
        W[15] = dpp_shl1(w[3]);
        #pragma unroll
        for (int d = 0; d < ND; ++d)
            #pragma unroll
            for (int i = 0; i < 8; ++i)
                acc[d][i] = fmaf(a[i], W[i + d], acc[d][i]);
    };

    // ---- depth-2 software pipeline, free-running (no barriers) ----
    LD(w0, a0);                               // chunk 0
    #pragma unroll 1
    for (int k = 0; k < NCHUNK; k += 2) {
        LD(w1, a1);                           // chunk k+1
        CMP(w0, a0);                          // chunk k
        if (k + 2 < NCHUNK) LD(w0, a0);       // chunk k+2
        CMP(w1, a1);                          // chunk k+1
    }

    // ---- epilogue: mean over C; OOB rows scale to exact zero ----
    const float sc = rok ? (1.0f / (float)CH) : 0.0f;
    float* outb = out + (size_t)b * NDISP * HW
                      + (size_t)(y0 + ly) * WW + xg * 8;
    #pragma unroll
    for (int d = 0; d < ND; ++d) {
        float* op = outb + (size_t)(dy * ND + d) * HW;
        float4 v0 = make_float4(acc[d][0] * sc, acc[d][1] * sc,
                                acc[d][2] * sc, acc[d][3] * sc);
        float4 v1 = make_float4(acc[d][4] * sc, acc[d][5] * sc,
                                acc[d][6] * sc, acc[d][7] * sc);
        *(float4*)(op)     = v0;
        *(float4*)(op + 4) = v1;
    }
}

extern "C" void kernel_launch(void* const* d_in, const int* in_sizes, int n_in,
                              void* d_out, int out_size, void* d_ws, size_t ws_size,
                              hipStream_t stream) {
    const float* in1 = (const float*)d_in[0];
    const float* in2 = (const float*)d_in[1];
    float* out = (float*)d_out;
    dim3 grid(BATCH, HH / TY);
    corr_kernel<<<grid, NT, 0, stream>>>(in1, in2, out);
}